// Round 9
// baseline (244.626 us; speedup 1.0000x reference)
//
#include <hip/hip_runtime.h>
#include <hip/hip_fp16.h>

#define D 64
#define BSHIFT 10              // nodes per bucket = 1024
#define BMASK ((1 << BSHIFT) - 1)
#define NBUK_MAX 256
#define T_TILE 6144            // edges per bin block (256 threads x 24)
#define EPT 24                 // edges per thread in bin phase
#define CAP 20480              // per-bucket srcs/ebuf capacity (mean 16327, sigma~127)

#if defined(__has_builtin)
#if __has_builtin(__builtin_amdgcn_fdot2)
#define HAVE_FDOT2 1
#endif
#endif

typedef _Float16 h2f __attribute__((ext_vector_type(2)));
typedef _Float16 half8v __attribute__((ext_vector_type(8)));
typedef float f4v __attribute__((ext_vector_type(4)));

// inclusive wave scan (64 lanes)
__device__ __forceinline__ int wave_iscan(int v, int lane) {
#pragma unroll
    for (int off = 1; off < 64; off <<= 1) {
        int u = __shfl_up(v, off, 64);
        if (lane >= off) v += u;
    }
    return v;
}

// block-wide (256 thr) exclusive scan; returns exclusive prefix
__device__ __forceinline__ int block_escan(int v, int tid, int* wtot /*>=4 ints LDS*/) {
    int lane = tid & 63, w = tid >> 6;
    int inc = wave_iscan(v, lane);
    if (lane == 63) wtot[w] = inc;
    __syncthreads();
    int addv = 0;
#pragma unroll
    for (int q = 0; q < 4; q++) addv += (q < w) ? wtot[q] : 0;
    return inc - v + addv;
}

__device__ __forceinline__ float4 h4_to_f4(uint2 u) {
    __half2 a = *(__half2*)&u.x, b = *(__half2*)&u.y;
    float2 fa = __half22float2(a), fb = __half22float2(b);
    return make_float4(fa.x, fa.y, fb.x, fb.y);
}

// acc[0..3] += fp16x4(u) — 4 v_dot2_f32_f16 when available
__device__ __forceinline__ void acc_u2(float* acc, uint2 u) {
#ifdef HAVE_FDOT2
    h2f a0, a1;
    __builtin_memcpy(&a0, &u.x, 4);
    __builtin_memcpy(&a1, &u.y, 4);
    const h2f LO = {(_Float16)1.0f, (_Float16)0.0f};
    const h2f HI = {(_Float16)0.0f, (_Float16)1.0f};
    acc[0] = __builtin_amdgcn_fdot2(a0, LO, acc[0], false);
    acc[1] = __builtin_amdgcn_fdot2(a0, HI, acc[1], false);
    acc[2] = __builtin_amdgcn_fdot2(a1, LO, acc[2], false);
    acc[3] = __builtin_amdgcn_fdot2(a1, HI, acc[3], false);
#else
    float4 v = h4_to_f4(u);
    acc[0] += v.x; acc[1] += v.y; acc[2] += v.z; acc[3] += v.w;
#endif
}

// acc[0..7] += fp16x8(u)
__device__ __forceinline__ void acc_u4(float* acc, uint4 u) {
    uint2 a; a.x = u.x; a.y = u.y;
    uint2 b; b.x = u.z; b.y = u.w;
    acc_u2(acc, a);
    acc_u2(acc + 4, b);
}

// ---------------- fused: bucket binning (blocks [0,nbin)) + X fp32->fp16 convert (rest) ----
// Binning and the feature convert are fully independent -> overlap.
// bin: packed entry (c & BMASK) << 18 | r — requires N <= 2^18 (N=200000 here);
// bucket b's region of ebuf is [b*CAP, b*CAP + cnt_b); bbase[b] (memset 0) ends as cnt_b.
// DIRECT scattered ebuf writes (no LDS stage): each block owns a contiguous run per bucket
// (bbase atomic), runs are block-exclusive byte ranges -> L2 merges partial lines; HBM write
// stays ~full-line (precedent: csr2b's srcs scatter, same pattern). Saves ~24K LDS ops/block
// and cuts LDS 34.8KB -> 8.2KB (4 -> 8 blocks/CU). Within-bucket order becomes atomic-order
// (downstream only needs bucket grouping).
// Edge data read ONCE via int4 (register-cached across phases). NO global per-node atomics
// (R3 lesson). bin blocks 0/1 additionally transpose W1/W2 -> global fp16 WT.

__global__ __launch_bounds__(256) void k_bin_conv(const int* __restrict__ row, const int* __restrict__ col,
                                                  int E, int nbin, int* __restrict__ bbase,
                                                  unsigned* __restrict__ ebuf, int nbuk,
                                                  const float* __restrict__ xu, const float* __restrict__ xj,
                                                  int U, int N,
                                                  const float* __restrict__ W1, const float* __restrict__ W2,
                                                  __half* __restrict__ WT1, __half* __restrict__ WT2,
                                                  __half* __restrict__ h) {
    __shared__ int hist4[4][NBUK_MAX];     // 4 KB
    __shared__ int cur4[4][NBUK_MAX];      // 4 KB — absolute ebuf cursors
    int tid = threadIdx.x;

    if ((int)blockIdx.x >= nbin) {
        // ---------- feature convert branch: 128 nodes/block, fp16(X) -> h ----------
        int m0 = ((int)blockIdx.x - nbin) * 128;
#pragma unroll
        for (int i = 0; i < 4; i++) {
            int slot = i * 256 + tid;          // 1024 slots = 128 nodes x 8 half8-chunks
            int nl = slot >> 3, q = slot & 7;
            int nn = m0 + nl;
            if (nn < N) {
                const float* src = (nn < U) ? (xu + (size_t)nn * D) : (xj + (size_t)(nn - U) * D);
                float4 a = *(const float4*)(src + q * 8);
                float4 b = *(const float4*)(src + q * 8 + 4);
                __half2 p0 = __floats2half2_rn(a.x, a.y);
                __half2 p1 = __floats2half2_rn(a.z, a.w);
                __half2 p2 = __floats2half2_rn(b.x, b.y);
                __half2 p3 = __floats2half2_rn(b.z, b.w);
                uint4 st;
                st.x = *(unsigned*)&p0; st.y = *(unsigned*)&p1;
                st.z = *(unsigned*)&p2; st.w = *(unsigned*)&p3;
                *(uint4*)(h + (size_t)nn * D + q * 8) = st;
            }
        }
        return;
    }

    // ---------- binning branch ----------
    int w = tid >> 6;
    int tile0 = blockIdx.x * T_TILE;
    int cnt = min(T_TILE, E - tile0);

    if (blockIdx.x < 2) {   // one-time W transpose: WT[c*64+k] = fp16(W[k*64+c])
        const float* Ws = blockIdx.x ? W2 : W1;
        __half* Wd = blockIdx.x ? WT2 : WT1;
#pragma unroll
        for (int i = 0; i < 16; i++) {
            int f = i * 256 + tid;           // f = k*64 + c
            int k = f >> 6, c = f & 63;
            Wd[c * 64 + k] = __float2half(Ws[f]);
        }
    }

    unsigned pk[EPT];
    int bk[EPT];

#pragma unroll
    for (int q = 0; q < 4; q++) hist4[q][tid] = 0;
    __syncthreads();
#pragma unroll
    for (int j = 0; j < EPT / 4; j++) {    // int4-vectorized edge read (order-free for binning)
        int i4 = j * 1024 + tid * 4;
        if (i4 + 3 < cnt) {
            int4 r4 = *(const int4*)(row + tile0 + i4);
            int4 c4 = *(const int4*)(col + tile0 + i4);
            int rr[4] = {r4.x, r4.y, r4.z, r4.w};
            int cc[4] = {c4.x, c4.y, c4.z, c4.w};
#pragma unroll
            for (int q = 0; q < 4; q++) {
                int jj = j * 4 + q;
                bk[jj] = cc[q] >> BSHIFT;
                pk[jj] = ((unsigned)(cc[q] & BMASK) << 18) | (unsigned)rr[q];
                atomicAdd(&hist4[w][bk[jj]], 1);
            }
        } else {
#pragma unroll
            for (int q = 0; q < 4; q++) {
                int jj = j * 4 + q;
                int i = i4 + q;
                if (i < cnt) {
                    int r = row[tile0 + i];
                    int c = col[tile0 + i];
                    bk[jj] = c >> BSHIFT;
                    pk[jj] = ((unsigned)(c & BMASK) << 18) | (unsigned)r;
                    atomicAdd(&hist4[w][bk[jj]], 1);
                } else {
                    bk[jj] = -1;
                }
            }
        }
    }
    __syncthreads();

    // tid = bucket id: reserve this block's run in bucket tid, set absolute per-wave cursors
    {
        int h0 = hist4[0][tid], h1 = hist4[1][tid], h2 = hist4[2][tid], h3 = hist4[3][tid];
        int v = h0 + h1 + h2 + h3;
        int base = tid * CAP;
        if (tid < nbuk && v > 0) base += atomicAdd(&bbase[tid], v);
        cur4[0][tid] = base;
        cur4[1][tid] = base + h0;
        cur4[2][tid] = base + h0 + h1;
        cur4[3][tid] = base + h0 + h1 + h2;
    }
    __syncthreads();

    // direct scattered ebuf write from register-cached edges
#pragma unroll
    for (int j = 0; j < EPT; j++) {
        if (bk[j] >= 0) {
            int p = atomicAdd(&cur4[w][bk[j]], 1);
            ebuf[p] = pk[j];
        }
    }
}

// ---------------- csr2a: per-bucket degree count + rps(start,end) + dinv + h sentinel -------

__global__ __launch_bounds__(256) void k_csr2a(const unsigned* __restrict__ ebuf,
                                               const int* __restrict__ bbase, int N,
                                               int2* __restrict__ rps, float* __restrict__ dinv,
                                               __half* __restrict__ h) {
    __shared__ int lcnt[1 << BSHIFT];  // 4 KB
    __shared__ int wtot[4];
    int tid = threadIdx.x;
    int c0 = blockIdx.x << BSHIFT;
    int nn = min(1 << BSHIFT, N - c0);
    int e0 = blockIdx.x * CAP, e1 = e0 + bbase[blockIdx.x];

    if (blockIdx.x == 0 && tid < 16) {  // zero h sentinel row (gather padding target)
        uint2 z; z.x = 0u; z.y = 0u;
        *(uint2*)(h + (size_t)N * D + tid * 4) = z;
    }

    for (int i = tid; i < (1 << BSHIFT); i += 256) lcnt[i] = 0;
    __syncthreads();
    int len = e1 - e0;
    int nf = len & ~3;
    for (int j = tid * 4; j < nf; j += 1024) {       // uint4-vectorized count
        uint4 v = *(const uint4*)(ebuf + e0 + j);
        atomicAdd(&lcnt[v.x >> 18], 1);
        atomicAdd(&lcnt[v.y >> 18], 1);
        atomicAdd(&lcnt[v.z >> 18], 1);
        atomicAdd(&lcnt[v.w >> 18], 1);
    }
    if (tid < (len - nf)) atomicAdd(&lcnt[ebuf[e0 + nf + tid] >> 18], 1);
    __syncthreads();

    int c[4]; int s = 0;
#pragma unroll
    for (int i = 0; i < 4; i++) { c[i] = lcnt[tid * 4 + i]; s += c[i]; }
    int run = block_escan(s, tid, wtot);
#pragma unroll
    for (int i = 0; i < 4; i++) {
        int idx = tid * 4 + i;
        if (idx < nn) {
            int st = e0 + run;
            rps[c0 + idx] = make_int2(st, st + c[i]);
            dinv[c0 + idx] = rsqrtf((float)(c[i] + 1));  // +1 self loop
        }
        run += c[i];
    }
}

// stage pre-transposed global WT (fp16, [c][k] dense 64x64) into LDS (stride 72).
__device__ __forceinline__ void stage_Wt(const __half* __restrict__ WTg, __half* __restrict__ Wt, int tid) {
#pragma unroll
    for (int i = 0; i < 2; i++) {
        int f = (i * 256 + tid) * 8;      // 4096 halves total
        int c = f >> 6, k = f & 63;
        *(half8v*)(Wt + c * 72 + k) = *(const half8v*)(WTg + f);
    }
}

// ---------------- fused: csr2b srcs scatter (blocks [0,nbuk)) + gemm layer-1 (rest) ----------
// gemm blocks: read fp16 features from h (in-place), MFMA with W1, scale by dinv, write h.

__global__ __launch_bounds__(256) void k_csr2b_gemm1(const unsigned* __restrict__ ebuf,
                                                     const int2* __restrict__ rps,
                                                     const int* __restrict__ bbase,
                                                     int N, int nbuk, int* __restrict__ srcs,
                                                     const __half* __restrict__ WT1,
                                                     const float* __restrict__ dinv, __half* __restrict__ h) {
    __shared__ __align__(16) __half Xh[64 * 72];   // bucket blocks alias lcur via Xh (4 KB)
    __shared__ __align__(16) __half Wt[64 * 72];
    int tid = threadIdx.x;
    if ((int)blockIdx.x < nbuk) {
        int* lcur = (int*)Xh;  // 4 KB of the 9.2 KB tile
        int c0 = blockIdx.x << BSHIFT;
        int e0 = blockIdx.x * CAP, e1 = e0 + bbase[blockIdx.x];
        for (int i = tid; i < (1 << BSHIFT); i += 256)
            lcur[i] = (c0 + i < N) ? rps[c0 + i].x : 0;
        __syncthreads();
        int len = e1 - e0;
        int nf = len & ~3;
        for (int j = tid * 4; j < nf; j += 1024) {   // uint4-vectorized scatter
            uint4 v = *(const uint4*)(ebuf + e0 + j);
            int p0 = atomicAdd(&lcur[v.x >> 18], 1); srcs[p0] = (int)(v.x & 0x3ffffu);
            int p1 = atomicAdd(&lcur[v.y >> 18], 1); srcs[p1] = (int)(v.y & 0x3ffffu);
            int p2 = atomicAdd(&lcur[v.z >> 18], 1); srcs[p2] = (int)(v.z & 0x3ffffu);
            int p3 = atomicAdd(&lcur[v.w >> 18], 1); srcs[p3] = (int)(v.w & 0x3ffffu);
        }
        if (tid < (len - nf)) {
            unsigned pk = ebuf[e0 + nf + tid];
            int p = atomicAdd(&lcur[pk >> 18], 1);
            srcs[p] = (int)(pk & 0x3ffffu);
        }
    } else {
        int n0 = ((int)blockIdx.x - nbuk) * 64;
        stage_Wt(WT1, Wt, tid);
#pragma unroll
        for (int i = 0; i < 2; i++) {
            int slot = i * 256 + tid;          // 512 slots = 64 nodes x 8 half8-chunks
            int nl = slot >> 3, q = slot & 7;
            int nn = n0 + nl;
            uint4 st; st.x = 0u; st.y = 0u; st.z = 0u; st.w = 0u;
            if (nn < N) st = *(const uint4*)(h + (size_t)nn * D + q * 8);
            *(uint4*)(Xh + nl * 72 + q * 8) = st;
        }
        __syncthreads();

        // MFMA: h[n][c] = fp16( dinv[n] * sum_k X[n][k] * W1[k][c] )  (in-place over features)
        int lane = tid & 63;
        int wv = tid >> 6;
        int n16 = lane & 15, quad = lane >> 4;
        const __half* Xw = Xh + (wv * 16) * 72;
        half8v a0 = *(const half8v*)(Xw + n16 * 72 + quad * 8);
        half8v a1 = *(const half8v*)(Xw + n16 * 72 + quad * 8 + 32);
        f4v acc[4];
#pragma unroll
        for (int ct = 0; ct < 4; ct++) {
            acc[ct] = (f4v){0.f, 0.f, 0.f, 0.f};
            const __half* wp = Wt + (ct * 16 + n16) * 72;
            half8v b0 = *(const half8v*)(wp + quad * 8);
            half8v b1 = *(const half8v*)(wp + quad * 8 + 32);
            acc[ct] = __builtin_amdgcn_mfma_f32_16x16x32_f16(a0, b0, acc[ct], 0, 0, 0);
            acc[ct] = __builtin_amdgcn_mfma_f32_16x16x32_f16(a1, b1, acc[ct], 0, 0, 0);
        }
#pragma unroll
        for (int r = 0; r < 4; r++) {
            int node = n0 + wv * 16 + quad * 4 + r;
            if (node < N) {
                float dv = dinv[node];
#pragma unroll
                for (int ct = 0; ct < 4; ct++)
                    h[(size_t)node * D + ct * 16 + n16] = __float2half(acc[ct][r] * dv);
            }
        }
    }
}

// ---------------- gather: 8 lanes per node, 8 nodes per wave-round ----------------
// lane = g*8+t; group g owns one node; lane t owns features [8t,8t+8) (uint4 = 16 B).
// 8 edge indices preloaded per group (sentinel N at load); all 8 dwordx4 gathers issued
// back-to-back (128 B in flight per lane). Proven optimal depth (R7: 16-deep was neutral
// on time and cost occupancy — agg is at the random-128B serving ceiling, not MLP-bound).

__device__ __forceinline__ void gather8(float* acc, const __half* __restrict__ hs,
                                        const int2* __restrict__ rps,
                                        const int* __restrict__ srcs,
                                        int node, int N, int g, int t) {
    const __half* hp = hs + t * 8;
    int2 r = rps[node];
    int e0 = r.x, deg = r.y - r.x;
    for (int cb = 0; cb < deg; cb += 8) {
        int sv = (cb + t < deg) ? srcs[e0 + cb + t] : N;
        int base = g * 8;
        int s0 = __shfl(sv, base + 0, 64);
        int s1 = __shfl(sv, base + 1, 64);
        int s2 = __shfl(sv, base + 2, 64);
        int s3 = __shfl(sv, base + 3, 64);
        int s4 = __shfl(sv, base + 4, 64);
        int s5 = __shfl(sv, base + 5, 64);
        int s6 = __shfl(sv, base + 6, 64);
        int s7 = __shfl(sv, base + 7, 64);
        uint4 u0 = *(const uint4*)(hp + (size_t)s0 * D);
        uint4 u1 = *(const uint4*)(hp + (size_t)s1 * D);
        uint4 u2 = *(const uint4*)(hp + (size_t)s2 * D);
        uint4 u3 = *(const uint4*)(hp + (size_t)s3 * D);
        uint4 u4 = *(const uint4*)(hp + (size_t)s4 * D);
        uint4 u5 = *(const uint4*)(hp + (size_t)s5 * D);
        uint4 u6 = *(const uint4*)(hp + (size_t)s6 * D);
        uint4 u7 = *(const uint4*)(hp + (size_t)s7 * D);
        acc_u4(acc, u0);
        acc_u4(acc, u1);
        acc_u4(acc, u2);
        acc_u4(acc, u3);
        acc_u4(acc, u4);
        acc_u4(acc, u5);
        acc_u4(acc, u6);
        acc_u4(acc, u7);
    }
}

// ---------------- fused: layer-1 aggregation + layer-2 gemm + z-projection epilogue --------
// agg: conv1 = (sum_s h[s] + h[c]) * dinv[c] + b1, relu'd into MFMA A-tile. MFMA with W2.
// Epilogue reduces the accumulator tile against pred weights, emitting per-node scalars
// zu[n] = dinv[n]*(A1[n]@W2)·pw_u and zj[n] (no hs2 materialization).

__global__ __launch_bounds__(256) void k_agg_gemm2(const __half* __restrict__ hs, const float* __restrict__ dinv,
                                                   const int2* __restrict__ rps, const int* __restrict__ srcs,
                                                   const float* __restrict__ bias, const __half* __restrict__ WT2,
                                                   const float* __restrict__ pw, int N,
                                                   float* __restrict__ zu, float* __restrict__ zj) {
    __shared__ __align__(16) __half Xh[64 * 72];
    __shared__ __align__(16) __half Wt[64 * 72];
    int tid = threadIdx.x;
    int lane = tid & 63;
    int w = tid >> 6;
    int g = lane >> 3, t = lane & 7;
    int n0 = blockIdx.x * 64;

    stage_Wt(WT2, Wt, tid);

    float4 ba = *(const float4*)(bias + t * 8);
    float4 bb = *(const float4*)(bias + t * 8 + 4);
#pragma unroll
    for (int rr = 0; rr < 2; rr++) {
        int nl = w * 16 + rr * 8 + g;
        int node = n0 + nl;
        uint4 st; st.x = 0u; st.y = 0u; st.z = 0u; st.w = 0u;
        if (node < N) {
            float acc[8] = {0.f, 0.f, 0.f, 0.f, 0.f, 0.f, 0.f, 0.f};
            gather8(acc, hs, rps, srcs, node, N, g, t);
            uint4 su = *(const uint4*)(hs + (size_t)node * D + t * 8);
            float4 sa = h4_to_f4(make_uint2(su.x, su.y));
            float4 sb = h4_to_f4(make_uint2(su.z, su.w));
            float dv = dinv[node];
            float o0 = fmaxf((acc[0] + sa.x) * dv + ba.x, 0.f);
            float o1 = fmaxf((acc[1] + sa.y) * dv + ba.y, 0.f);
            float o2 = fmaxf((acc[2] + sa.z) * dv + ba.z, 0.f);
            float o3 = fmaxf((acc[3] + sa.w) * dv + ba.w, 0.f);
            float o4 = fmaxf((acc[4] + sb.x) * dv + bb.x, 0.f);
            float o5 = fmaxf((acc[5] + sb.y) * dv + bb.y, 0.f);
            float o6 = fmaxf((acc[6] + sb.z) * dv + bb.z, 0.f);
            float o7 = fmaxf((acc[7] + sb.w) * dv + bb.w, 0.f);
            __half2 p0 = __floats2half2_rn(o0, o1);
            __half2 p1 = __floats2half2_rn(o2, o3);
            __half2 p2 = __floats2half2_rn(o4, o5);
            __half2 p3 = __floats2half2_rn(o6, o7);
            st.x = *(unsigned*)&p0; st.y = *(unsigned*)&p1;
            st.z = *(unsigned*)&p2; st.w = *(unsigned*)&p3;
        }
        *(uint4*)(Xh + nl * 72 + t * 8) = st;
    }
    __syncthreads();

    // ---- MFMA with W2 + z-projection epilogue (no hs2 write) ----
    int wv = w;
    int n16 = lane & 15, quad = lane >> 4;
    const __half* Xw = Xh + (wv * 16) * 72;
    half8v a0 = *(const half8v*)(Xw + n16 * 72 + quad * 8);
    half8v a1 = *(const half8v*)(Xw + n16 * 72 + quad * 8 + 32);
    f4v acc[4];
    float pwu_r[4], pwj_r[4];
#pragma unroll
    for (int ct = 0; ct < 4; ct++) {
        pwu_r[ct] = pw[ct * 16 + n16];
        pwj_r[ct] = pw[64 + ct * 16 + n16];
        acc[ct] = (f4v){0.f, 0.f, 0.f, 0.f};
        const __half* wp = Wt + (ct * 16 + n16) * 72;
        half8v b0 = *(const half8v*)(wp + quad * 8);
        half8v b1 = *(const half8v*)(wp + quad * 8 + 32);
        acc[ct] = __builtin_amdgcn_mfma_f32_16x16x32_f16(a0, b0, acc[ct], 0, 0, 0);
        acc[ct] = __builtin_amdgcn_mfma_f32_16x16x32_f16(a1, b1, acc[ct], 0, 0, 0);
    }
#pragma unroll
    for (int r = 0; r < 4; r++) {
        int node = n0 + wv * 16 + quad * 4 + r;
        float dv = (node < N) ? dinv[node] : 0.0f;
        float su = acc[0][r] * pwu_r[0] + acc[1][r] * pwu_r[1]
                 + acc[2][r] * pwu_r[2] + acc[3][r] * pwu_r[3];
        float sj = acc[0][r] * pwj_r[0] + acc[1][r] * pwj_r[1]
                 + acc[2][r] * pwj_r[2] + acc[3][r] * pwj_r[3];
        su += __shfl_xor(su, 1, 64); sj += __shfl_xor(sj, 1, 64);
        su += __shfl_xor(su, 2, 64); sj += __shfl_xor(sj, 2, 64);
        su += __shfl_xor(su, 4, 64); sj += __shfl_xor(sj, 4, 64);
        su += __shfl_xor(su, 8, 64); sj += __shfl_xor(sj, 8, 64);
        if (n16 == 0 && node < N) {
            zu[node] = su * dv;
            zj[node] = sj * dv;
        }
    }
}

// ---------------- layer-2 aggregation + prediction over scalar z tables --------------------
// out[p] = (sum_s zu[s] + zu[u])*dinv[u] + b2·pw_u + (sum_s zj[s] + zj[j])*dinv[j] + b2·pw_j + pb

__global__ __launch_bounds__(256) void k_pred(const float* __restrict__ zu, const float* __restrict__ zj,
                                              const float* __restrict__ dinv,
                                              const int2* __restrict__ rps, const int* __restrict__ srcs,
                                              const float* __restrict__ b2, const float* __restrict__ pw,
                                              const float* __restrict__ pb,
                                              const int* __restrict__ uidx, const int* __restrict__ jidx,
                                              int U, int N, int B, float* __restrict__ out) {
    int tid = threadIdx.x;
    int lane = tid & 63;
    int g = lane >> 3, t = lane & 7;
    int pair = blockIdx.x * 16 + (tid >> 6) * 4 + (g >> 1);
    if (pair >= B) return;
    int side = g & 1;
    int c = side ? (U + jidx[pair]) : uidx[pair];
    const float* zt = side ? zj : zu;

    float4 b2a = *(const float4*)(b2 + t * 8);
    float4 b2b = *(const float4*)(b2 + t * 8 + 4);
    float4 wa = *(const float4*)(pw + side * 64 + t * 8);
    float4 wb = *(const float4*)(pw + side * 64 + t * 8 + 4);
    float cpart = b2a.x * wa.x + b2a.y * wa.y + b2a.z * wa.z + b2a.w * wa.w
                + b2b.x * wb.x + b2b.y * wb.y + b2b.z * wb.z + b2b.w * wb.w;

    int2 r = rps[c];
    int deg = r.y - r.x;
    float s = 0.f;
    for (int cb = 0; cb < deg; cb += 8) {
        if (cb + t < deg) s += zt[srcs[r.x + cb + t]];
    }
    s += __shfl_xor(s, 1, 64); cpart += __shfl_xor(cpart, 1, 64);
    s += __shfl_xor(s, 2, 64); cpart += __shfl_xor(cpart, 2, 64);
    s += __shfl_xor(s, 4, 64); cpart += __shfl_xor(cpart, 4, 64);

    float val = (s + zt[c]) * dinv[c] + cpart;
    val += __shfl_xor(val, 8, 64);   // combine user+job sides of this pair
    if ((lane & 15) == 0) out[pair] = val + pb[0];
}

// ---------------- host ----------------

extern "C" void kernel_launch(void* const* d_in, const int* in_sizes, int n_in,
                              void* d_out, int out_size, void* d_ws, size_t ws_size,
                              hipStream_t stream) {
    const int*   edge = (const int*)d_in[0];
    const int*   uidx = (const int*)d_in[1];
    const int*   jidx = (const int*)d_in[2];
    const float* xu   = (const float*)d_in[3];
    const float* xj   = (const float*)d_in[4];
    const float* W1   = (const float*)d_in[5];
    const float* b1   = (const float*)d_in[6];
    const float* W2   = (const float*)d_in[7];
    const float* b2   = (const float*)d_in[8];
    const float* pw   = (const float*)d_in[9];
    const float* pb   = (const float*)d_in[10];
    float* out = (float*)d_out;

    int E = in_sizes[0] / 2;
    int B = in_sizes[1];
    int U = in_sizes[3] / D;
    int J = in_sizes[4] / D;
    int N = U + J;
    int nbuk = (N + (1 << BSHIFT) - 1) >> BSHIFT;   // 196 for N=200000; must be <= 256
    int nbin = (E + T_TILE - 1) / T_TILE;           // 521
    int nconv = (N + 127) / 128;                    // 1563 convert blocks
    const int* row = edge;       // sources
    const int* col = edge + E;   // targets

    char* p = (char*)d_ws;
    auto alloc = [&](size_t bytes) -> void* {
        void* q = (void*)p;
        p += (bytes + 255) / 256 * 256;
        return q;
    };
    size_t capsz = (size_t)nbuk * CAP * 4;               // 16.06 MB
    int*      bbase = (int*)alloc(256 * 4);
    int2*     rps   = (int2*)alloc((size_t)N * 8);
    float*    dinv  = (float*)alloc((size_t)N * 4);
    int*      srcs  = (int*)alloc(capsz);
    __half*   h     = (__half*)alloc((size_t)(N + 1) * D * 2);  // features->hidden, in-place (+ sentinel)
    unsigned* ebuf  = (unsigned*)alloc(capsz);
    float*    zu    = (float*)alloc((size_t)N * 4);      // per-node conv2·pw_u scalars
    float*    zj    = (float*)alloc((size_t)N * 4);      // per-node conv2·pw_j scalars
    __half*   WT1   = (__half*)alloc((size_t)D * D * 2); // pre-transposed W1 (fp16)
    __half*   WT2   = (__half*)alloc((size_t)D * D * 2); // pre-transposed W2 (fp16)

    hipMemsetAsync(bbase, 0, 256 * 4, stream);

    // K1: binning (521 blocks, direct-scatter ebuf, 8.2KB LDS) ∥ X fp32->fp16 convert (1563)
    // — fully independent phases; bin blocks 0/1 also transpose W1/W2 -> WT1/WT2
    k_bin_conv<<<nbin + nconv, 256, 0, stream>>>(row, col, E, nbin, bbase, ebuf, nbuk,
                                                 xu, xj, U, N, W1, W2, WT1, WT2, h);

    // K2: per-bucket degree count -> rps + dinv (+ h sentinel), 196 blocks (short)
    k_csr2a<<<nbuk, 256, 0, stream>>>(ebuf, bbase, N, rps, dinv, h);

    // K3: srcs scatter (196 blocks) ∥ layer-1 gemm from fp16 features, in-place h (3125 blocks)
    k_csr2b_gemm1<<<nbuk + (N + 63) / 64, 256, 0, stream>>>(ebuf, rps, bbase, N, nbuk, srcs,
                                                            WT1, dinv, h);

    // K4: layer-1 aggregation (8-deep gather) + layer-2 gemm + z-projection
    k_agg_gemm2<<<(N + 63) / 64, 256, 0, stream>>>(h, dinv, rps, srcs, b1, WT2, pw, N, zu, zj);

    // K5: layer-2 aggregation over scalar z tables fused with predictor
    k_pred<<<(B + 15) / 16, 256, 0, stream>>>(zu, zj, dinv, rps, srcs, b2, pw, pb,
                                              uidx, jidx, U, N, B, out);
}

// Round 10
// 234.071 us; speedup vs baseline: 1.0451x; 1.0451x over previous
//
#include <hip/hip_runtime.h>
#include <hip/hip_fp16.h>

#define D 64
#define BSHIFT 10              // nodes per bucket = 1024
#define BMASK ((1 << BSHIFT) - 1)
#define NBUK_MAX 256
#define T_TILE 6144            // edges per bin block (256 threads x 24)
#define EPT 24                 // edges per thread in bin phase
#define CAP 20480              // per-bucket srcs/ebuf capacity (mean 16327, sigma~127)

#if defined(__has_builtin)
#if __has_builtin(__builtin_amdgcn_fdot2)
#define HAVE_FDOT2 1
#endif
#endif

typedef _Float16 h2f __attribute__((ext_vector_type(2)));
typedef _Float16 half8v __attribute__((ext_vector_type(8)));
typedef float f4v __attribute__((ext_vector_type(4)));

// inclusive wave scan (64 lanes)
__device__ __forceinline__ int wave_iscan(int v, int lane) {
#pragma unroll
    for (int off = 1; off < 64; off <<= 1) {
        int u = __shfl_up(v, off, 64);
        if (lane >= off) v += u;
    }
    return v;
}

// block-wide (256 thr) exclusive scan; returns exclusive prefix
__device__ __forceinline__ int block_escan(int v, int tid, int* wtot /*>=4 ints LDS*/) {
    int lane = tid & 63, w = tid >> 6;
    int inc = wave_iscan(v, lane);
    if (lane == 63) wtot[w] = inc;
    __syncthreads();
    int addv = 0;
#pragma unroll
    for (int q = 0; q < 4; q++) addv += (q < w) ? wtot[q] : 0;
    return inc - v + addv;
}

__device__ __forceinline__ float4 h4_to_f4(uint2 u) {
    __half2 a = *(__half2*)&u.x, b = *(__half2*)&u.y;
    float2 fa = __half22float2(a), fb = __half22float2(b);
    return make_float4(fa.x, fa.y, fb.x, fb.y);
}

// acc[0..3] += fp16x4(u) — 4 v_dot2_f32_f16 when available
__device__ __forceinline__ void acc_u2(float* acc, uint2 u) {
#ifdef HAVE_FDOT2
    h2f a0, a1;
    __builtin_memcpy(&a0, &u.x, 4);
    __builtin_memcpy(&a1, &u.y, 4);
    const h2f LO = {(_Float16)1.0f, (_Float16)0.0f};
    const h2f HI = {(_Float16)0.0f, (_Float16)1.0f};
    acc[0] = __builtin_amdgcn_fdot2(a0, LO, acc[0], false);
    acc[1] = __builtin_amdgcn_fdot2(a0, HI, acc[1], false);
    acc[2] = __builtin_amdgcn_fdot2(a1, LO, acc[2], false);
    acc[3] = __builtin_amdgcn_fdot2(a1, HI, acc[3], false);
#else
    float4 v = h4_to_f4(u);
    acc[0] += v.x; acc[1] += v.y; acc[2] += v.z; acc[3] += v.w;
#endif
}

// acc[0..7] += fp16x8(u)
__device__ __forceinline__ void acc_u4(float* acc, uint4 u) {
    uint2 a; a.x = u.x; a.y = u.y;
    uint2 b; b.x = u.z; b.y = u.w;
    acc_u2(acc, a);
    acc_u2(acc + 4, b);
}

// ---------------- fused: bucket binning (blocks [0,nbin)) + X fp32->fp16 convert (rest) ----
// Binning and the feature convert are fully independent -> overlap.
// bin: packed entry (c & BMASK) << 18 | r — requires N <= 2^18 (N=200000 here);
// bucket b's region of ebuf is [b*CAP, b*CAP + cnt_b); bbase[b] (memset 0) ends as cnt_b.
// STAGED LDS reorder for the ebuf write is essential (R9 lesson: direct 4B scatters cost
// +7us despite 2x occupancy — per-bucket runs avg 125B ~ full line only via the stage).
// Edge data read ONCE via int4 (register-cached across phases). NO global per-node atomics
// (R3 lesson). bin blocks 0/1 additionally transpose W1/W2 -> global fp16 WT.

__global__ __launch_bounds__(256) void k_bin_conv(const int* __restrict__ row, const int* __restrict__ col,
                                                  int E, int nbin, int* __restrict__ bbase,
                                                  unsigned* __restrict__ ebuf, int nbuk,
                                                  const float* __restrict__ xu, const float* __restrict__ xj,
                                                  int U, int N,
                                                  const float* __restrict__ W1, const float* __restrict__ W2,
                                                  __half* __restrict__ WT1, __half* __restrict__ WT2,
                                                  __half* __restrict__ h) {
    __shared__ int hist4[4][NBUK_MAX];     // 4 KB
    __shared__ int sexcl[NBUK_MAX];
    __shared__ int cur4[4][NBUK_MAX];      // 4 KB
    __shared__ int gbase[NBUK_MAX];
    __shared__ int wtot[4];
    __shared__ unsigned stage[T_TILE];     // 24 KB
    __shared__ unsigned char sbuk[T_TILE]; // 6 KB
    int tid = threadIdx.x;

    if ((int)blockIdx.x >= nbin) {
        // ---------- feature convert branch: 128 nodes/block, fp16(X) -> h ----------
        int m0 = ((int)blockIdx.x - nbin) * 128;
#pragma unroll
        for (int i = 0; i < 4; i++) {
            int slot = i * 256 + tid;          // 1024 slots = 128 nodes x 8 half8-chunks
            int nl = slot >> 3, q = slot & 7;
            int nn = m0 + nl;
            if (nn < N) {
                const float* src = (nn < U) ? (xu + (size_t)nn * D) : (xj + (size_t)(nn - U) * D);
                float4 a = *(const float4*)(src + q * 8);
                float4 b = *(const float4*)(src + q * 8 + 4);
                __half2 p0 = __floats2half2_rn(a.x, a.y);
                __half2 p1 = __floats2half2_rn(a.z, a.w);
                __half2 p2 = __floats2half2_rn(b.x, b.y);
                __half2 p3 = __floats2half2_rn(b.z, b.w);
                uint4 st;
                st.x = *(unsigned*)&p0; st.y = *(unsigned*)&p1;
                st.z = *(unsigned*)&p2; st.w = *(unsigned*)&p3;
                *(uint4*)(h + (size_t)nn * D + q * 8) = st;
            }
        }
        return;
    }

    // ---------- binning branch ----------
    int w = tid >> 6;
    int tile0 = blockIdx.x * T_TILE;
    int cnt = min(T_TILE, E - tile0);

    if (blockIdx.x < 2) {   // one-time W transpose: WT[c*64+k] = fp16(W[k*64+c])
        const float* Ws = blockIdx.x ? W2 : W1;
        __half* Wd = blockIdx.x ? WT2 : WT1;
#pragma unroll
        for (int i = 0; i < 16; i++) {
            int f = i * 256 + tid;           // f = k*64 + c
            int k = f >> 6, c = f & 63;
            Wd[c * 64 + k] = __float2half(Ws[f]);
        }
    }

    unsigned pk[EPT];
    int bk[EPT];

#pragma unroll
    for (int q = 0; q < 4; q++) hist4[q][tid] = 0;
    __syncthreads();
#pragma unroll
    for (int j = 0; j < EPT / 4; j++) {    // int4-vectorized edge read (order-free for binning)
        int i4 = j * 1024 + tid * 4;
        if (i4 + 3 < cnt) {
            int4 r4 = *(const int4*)(row + tile0 + i4);
            int4 c4 = *(const int4*)(col + tile0 + i4);
            int rr[4] = {r4.x, r4.y, r4.z, r4.w};
            int cc[4] = {c4.x, c4.y, c4.z, c4.w};
#pragma unroll
            for (int q = 0; q < 4; q++) {
                int jj = j * 4 + q;
                bk[jj] = cc[q] >> BSHIFT;
                pk[jj] = ((unsigned)(cc[q] & BMASK) << 18) | (unsigned)rr[q];
                atomicAdd(&hist4[w][bk[jj]], 1);
            }
        } else {
#pragma unroll
            for (int q = 0; q < 4; q++) {
                int jj = j * 4 + q;
                int i = i4 + q;
                if (i < cnt) {
                    int r = row[tile0 + i];
                    int c = col[tile0 + i];
                    bk[jj] = c >> BSHIFT;
                    pk[jj] = ((unsigned)(c & BMASK) << 18) | (unsigned)r;
                    atomicAdd(&hist4[w][bk[jj]], 1);
                } else {
                    bk[jj] = -1;
                }
            }
        }
    }
    __syncthreads();

    int h0 = hist4[0][tid], h1 = hist4[1][tid], h2 = hist4[2][tid], h3 = hist4[3][tid];
    int v = h0 + h1 + h2 + h3;
    int excl = block_escan(v, tid, wtot);
    sexcl[tid] = excl;
    cur4[0][tid] = excl;
    cur4[1][tid] = excl + h0;
    cur4[2][tid] = excl + h0 + h1;
    cur4[3][tid] = excl + h0 + h1 + h2;
    gbase[tid] = (v > 0 && tid < nbuk) ? (tid * CAP + atomicAdd(&bbase[tid], v)) : 0;
    __syncthreads();

#pragma unroll
    for (int j = 0; j < EPT; j++) {
        if (bk[j] >= 0) {
            int p = atomicAdd(&cur4[w][bk[j]], 1);
            stage[p] = pk[j];
            sbuk[p] = (unsigned char)bk[j];
        }
    }
    __syncthreads();

    for (int i = tid; i < cnt; i += 256) {
        int b = sbuk[i];
        int gpos = gbase[b] + (i - sexcl[b]);
        ebuf[gpos] = stage[i];
    }
}

// ---------------- csr2a: per-bucket degree count + rps(start,end) + dinv + h sentinel -------
// 1024 threads/block (R9->R10 fix): 196 blocks at 256thr was 3 waves/CU machine-wide —
// pure latency-bound underutilization. 16 waves/block -> 12 waves/CU, 4x loads+atomics
// in flight. One thread per node; scan generalized to 16 waves.

__global__ __launch_bounds__(1024) void k_csr2a(const unsigned* __restrict__ ebuf,
                                                const int* __restrict__ bbase, int N,
                                                int2* __restrict__ rps, float* __restrict__ dinv,
                                                __half* __restrict__ h) {
    __shared__ int lcnt[1 << BSHIFT];  // 4 KB
    __shared__ int wtot[16];
    int tid = threadIdx.x;
    int c0 = blockIdx.x << BSHIFT;
    int nn = min(1 << BSHIFT, N - c0);
    int e0 = blockIdx.x * CAP, e1 = e0 + bbase[blockIdx.x];

    if (blockIdx.x == 0 && tid < 16) {  // zero h sentinel row (gather padding target)
        uint2 z; z.x = 0u; z.y = 0u;
        *(uint2*)(h + (size_t)N * D + tid * 4) = z;
    }

    lcnt[tid] = 0;
    __syncthreads();
    int len = e1 - e0;
    int nf = len & ~3;
    for (int j = tid * 4; j < nf; j += 4096) {       // uint4-vectorized count
        uint4 v = *(const uint4*)(ebuf + e0 + j);
        atomicAdd(&lcnt[v.x >> 18], 1);
        atomicAdd(&lcnt[v.y >> 18], 1);
        atomicAdd(&lcnt[v.z >> 18], 1);
        atomicAdd(&lcnt[v.w >> 18], 1);
    }
    if (tid < (len - nf)) atomicAdd(&lcnt[ebuf[e0 + nf + tid] >> 18], 1);
    __syncthreads();

    // 1024-thread exclusive scan (one node per thread)
    int c = lcnt[tid];
    int lane = tid & 63, w = tid >> 6;
    int inc = wave_iscan(c, lane);
    if (lane == 63) wtot[w] = inc;
    __syncthreads();
    int addv = 0;
#pragma unroll
    for (int q = 0; q < 16; q++) addv += (q < w) ? wtot[q] : 0;
    int excl = inc - c + addv;

    if (tid < nn) {
        int st = e0 + excl;
        rps[c0 + tid] = make_int2(st, st + c);
        dinv[c0 + tid] = rsqrtf((float)(c + 1));  // +1 self loop
    }
}

// stage pre-transposed global WT (fp16, [c][k] dense 64x64) into LDS (stride 72).
__device__ __forceinline__ void stage_Wt(const __half* __restrict__ WTg, __half* __restrict__ Wt, int tid) {
#pragma unroll
    for (int i = 0; i < 2; i++) {
        int f = (i * 256 + tid) * 8;      // 4096 halves total
        int c = f >> 6, k = f & 63;
        *(half8v*)(Wt + c * 72 + k) = *(const half8v*)(WTg + f);
    }
}

// ---------------- fused: csr2b srcs scatter (blocks [0,nbuk)) + gemm layer-1 (rest) ----------
// gemm blocks: read fp16 features from h (in-place), MFMA with W1, scale by dinv, write h.

__global__ __launch_bounds__(256) void k_csr2b_gemm1(const unsigned* __restrict__ ebuf,
                                                     const int2* __restrict__ rps,
                                                     const int* __restrict__ bbase,
                                                     int N, int nbuk, int* __restrict__ srcs,
                                                     const __half* __restrict__ WT1,
                                                     const float* __restrict__ dinv, __half* __restrict__ h) {
    __shared__ __align__(16) __half Xh[64 * 72];   // bucket blocks alias lcur via Xh (4 KB)
    __shared__ __align__(16) __half Wt[64 * 72];
    int tid = threadIdx.x;
    if ((int)blockIdx.x < nbuk) {
        int* lcur = (int*)Xh;  // 4 KB of the 9.2 KB tile
        int c0 = blockIdx.x << BSHIFT;
        int e0 = blockIdx.x * CAP, e1 = e0 + bbase[blockIdx.x];
        for (int i = tid; i < (1 << BSHIFT); i += 256)
            lcur[i] = (c0 + i < N) ? rps[c0 + i].x : 0;
        __syncthreads();
        int len = e1 - e0;
        int nf = len & ~3;
        for (int j = tid * 4; j < nf; j += 1024) {   // uint4-vectorized scatter
            uint4 v = *(const uint4*)(ebuf + e0 + j);
            int p0 = atomicAdd(&lcur[v.x >> 18], 1); srcs[p0] = (int)(v.x & 0x3ffffu);
            int p1 = atomicAdd(&lcur[v.y >> 18], 1); srcs[p1] = (int)(v.y & 0x3ffffu);
            int p2 = atomicAdd(&lcur[v.z >> 18], 1); srcs[p2] = (int)(v.z & 0x3ffffu);
            int p3 = atomicAdd(&lcur[v.w >> 18], 1); srcs[p3] = (int)(v.w & 0x3ffffu);
        }
        if (tid < (len - nf)) {
            unsigned pk = ebuf[e0 + nf + tid];
            int p = atomicAdd(&lcur[pk >> 18], 1);
            srcs[p] = (int)(pk & 0x3ffffu);
        }
    } else {
        int n0 = ((int)blockIdx.x - nbuk) * 64;
        stage_Wt(WT1, Wt, tid);
#pragma unroll
        for (int i = 0; i < 2; i++) {
            int slot = i * 256 + tid;          // 512 slots = 64 nodes x 8 half8-chunks
            int nl = slot >> 3, q = slot & 7;
            int nn = n0 + nl;
            uint4 st; st.x = 0u; st.y = 0u; st.z = 0u; st.w = 0u;
            if (nn < N) st = *(const uint4*)(h + (size_t)nn * D + q * 8);
            *(uint4*)(Xh + nl * 72 + q * 8) = st;
        }
        __syncthreads();

        // MFMA: h[n][c] = fp16( dinv[n] * sum_k X[n][k] * W1[k][c] )  (in-place over features)
        int lane = tid & 63;
        int wv = tid >> 6;
        int n16 = lane & 15, quad = lane >> 4;
        const __half* Xw = Xh + (wv * 16) * 72;
        half8v a0 = *(const half8v*)(Xw + n16 * 72 + quad * 8);
        half8v a1 = *(const half8v*)(Xw + n16 * 72 + quad * 8 + 32);
        f4v acc[4];
#pragma unroll
        for (int ct = 0; ct < 4; ct++) {
            acc[ct] = (f4v){0.f, 0.f, 0.f, 0.f};
            const __half* wp = Wt + (ct * 16 + n16) * 72;
            half8v b0 = *(const half8v*)(wp + quad * 8);
            half8v b1 = *(const half8v*)(wp + quad * 8 + 32);
            acc[ct] = __builtin_amdgcn_mfma_f32_16x16x32_f16(a0, b0, acc[ct], 0, 0, 0);
            acc[ct] = __builtin_amdgcn_mfma_f32_16x16x32_f16(a1, b1, acc[ct], 0, 0, 0);
        }
#pragma unroll
        for (int r = 0; r < 4; r++) {
            int node = n0 + wv * 16 + quad * 4 + r;
            if (node < N) {
                float dv = dinv[node];
#pragma unroll
                for (int ct = 0; ct < 4; ct++)
                    h[(size_t)node * D + ct * 16 + n16] = __float2half(acc[ct][r] * dv);
            }
        }
    }
}

// ---------------- gather: 8 lanes per node, 8 nodes per wave-round ----------------
// lane = g*8+t; group g owns one node; lane t owns features [8t,8t+8) (uint4 = 16 B).
// 8 edge indices preloaded per group (sentinel N at load); all 8 dwordx4 gathers issued
// back-to-back (128 B in flight per lane). Proven optimal depth (R7: 16-deep was neutral
// on time and cost occupancy — agg is at the random-128B serving ceiling, not MLP-bound).

__device__ __forceinline__ void gather8(float* acc, const __half* __restrict__ hs,
                                        const int2* __restrict__ rps,
                                        const int* __restrict__ srcs,
                                        int node, int N, int g, int t) {
    const __half* hp = hs + t * 8;
    int2 r = rps[node];
    int e0 = r.x, deg = r.y - r.x;
    for (int cb = 0; cb < deg; cb += 8) {
        int sv = (cb + t < deg) ? srcs[e0 + cb + t] : N;
        int base = g * 8;
        int s0 = __shfl(sv, base + 0, 64);
        int s1 = __shfl(sv, base + 1, 64);
        int s2 = __shfl(sv, base + 2, 64);
        int s3 = __shfl(sv, base + 3, 64);
        int s4 = __shfl(sv, base + 4, 64);
        int s5 = __shfl(sv, base + 5, 64);
        int s6 = __shfl(sv, base + 6, 64);
        int s7 = __shfl(sv, base + 7, 64);
        uint4 u0 = *(const uint4*)(hp + (size_t)s0 * D);
        uint4 u1 = *(const uint4*)(hp + (size_t)s1 * D);
        uint4 u2 = *(const uint4*)(hp + (size_t)s2 * D);
        uint4 u3 = *(const uint4*)(hp + (size_t)s3 * D);
        uint4 u4 = *(const uint4*)(hp + (size_t)s4 * D);
        uint4 u5 = *(const uint4*)(hp + (size_t)s5 * D);
        uint4 u6 = *(const uint4*)(hp + (size_t)s6 * D);
        uint4 u7 = *(const uint4*)(hp + (size_t)s7 * D);
        acc_u4(acc, u0);
        acc_u4(acc, u1);
        acc_u4(acc, u2);
        acc_u4(acc, u3);
        acc_u4(acc, u4);
        acc_u4(acc, u5);
        acc_u4(acc, u6);
        acc_u4(acc, u7);
    }
}

// ---------------- fused: layer-1 aggregation + layer-2 gemm + z-projection epilogue --------
// agg: conv1 = (sum_s h[s] + h[c]) * dinv[c] + b1, relu'd into MFMA A-tile. MFMA with W2.
// Epilogue reduces the accumulator tile against pred weights, emitting per-node scalars
// zu[n] = dinv[n]*(A1[n]@W2)·pw_u and zj[n] (no hs2 materialization).

__global__ __launch_bounds__(256) void k_agg_gemm2(const __half* __restrict__ hs, const float* __restrict__ dinv,
                                                   const int2* __restrict__ rps, const int* __restrict__ srcs,
                                                   const float* __restrict__ bias, const __half* __restrict__ WT2,
                                                   const float* __restrict__ pw, int N,
                                                   float* __restrict__ zu, float* __restrict__ zj) {
    __shared__ __align__(16) __half Xh[64 * 72];
    __shared__ __align__(16) __half Wt[64 * 72];
    int tid = threadIdx.x;
    int lane = tid & 63;
    int w = tid >> 6;
    int g = lane >> 3, t = lane & 7;
    int n0 = blockIdx.x * 64;

    stage_Wt(WT2, Wt, tid);

    float4 ba = *(const float4*)(bias + t * 8);
    float4 bb = *(const float4*)(bias + t * 8 + 4);
#pragma unroll
    for (int rr = 0; rr < 2; rr++) {
        int nl = w * 16 + rr * 8 + g;
        int node = n0 + nl;
        uint4 st; st.x = 0u; st.y = 0u; st.z = 0u; st.w = 0u;
        if (node < N) {
            float acc[8] = {0.f, 0.f, 0.f, 0.f, 0.f, 0.f, 0.f, 0.f};
            gather8(acc, hs, rps, srcs, node, N, g, t);
            uint4 su = *(const uint4*)(hs + (size_t)node * D + t * 8);
            float4 sa = h4_to_f4(make_uint2(su.x, su.y));
            float4 sb = h4_to_f4(make_uint2(su.z, su.w));
            float dv = dinv[node];
            float o0 = fmaxf((acc[0] + sa.x) * dv + ba.x, 0.f);
            float o1 = fmaxf((acc[1] + sa.y) * dv + ba.y, 0.f);
            float o2 = fmaxf((acc[2] + sa.z) * dv + ba.z, 0.f);
            float o3 = fmaxf((acc[3] + sa.w) * dv + ba.w, 0.f);
            float o4 = fmaxf((acc[4] + sb.x) * dv + bb.x, 0.f);
            float o5 = fmaxf((acc[5] + sb.y) * dv + bb.y, 0.f);
            float o6 = fmaxf((acc[6] + sb.z) * dv + bb.z, 0.f);
            float o7 = fmaxf((acc[7] + sb.w) * dv + bb.w, 0.f);
            __half2 p0 = __floats2half2_rn(o0, o1);
            __half2 p1 = __floats2half2_rn(o2, o3);
            __half2 p2 = __floats2half2_rn(o4, o5);
            __half2 p3 = __floats2half2_rn(o6, o7);
            st.x = *(unsigned*)&p0; st.y = *(unsigned*)&p1;
            st.z = *(unsigned*)&p2; st.w = *(unsigned*)&p3;
        }
        *(uint4*)(Xh + nl * 72 + t * 8) = st;
    }
    __syncthreads();

    // ---- MFMA with W2 + z-projection epilogue (no hs2 write) ----
    int wv = w;
    int n16 = lane & 15, quad = lane >> 4;
    const __half* Xw = Xh + (wv * 16) * 72;
    half8v a0 = *(const half8v*)(Xw + n16 * 72 + quad * 8);
    half8v a1 = *(const half8v*)(Xw + n16 * 72 + quad * 8 + 32);
    f4v acc[4];
    float pwu_r[4], pwj_r[4];
#pragma unroll
    for (int ct = 0; ct < 4; ct++) {
        pwu_r[ct] = pw[ct * 16 + n16];
        pwj_r[ct] = pw[64 + ct * 16 + n16];
        acc[ct] = (f4v){0.f, 0.f, 0.f, 0.f};
        const __half* wp = Wt + (ct * 16 + n16) * 72;
        half8v b0 = *(const half8v*)(wp + quad * 8);
        half8v b1 = *(const half8v*)(wp + quad * 8 + 32);
        acc[ct] = __builtin_amdgcn_mfma_f32_16x16x32_f16(a0, b0, acc[ct], 0, 0, 0);
        acc[ct] = __builtin_amdgcn_mfma_f32_16x16x32_f16(a1, b1, acc[ct], 0, 0, 0);
    }
#pragma unroll
    for (int r = 0; r < 4; r++) {
        int node = n0 + wv * 16 + quad * 4 + r;
        float dv = (node < N) ? dinv[node] : 0.0f;
        float su = acc[0][r] * pwu_r[0] + acc[1][r] * pwu_r[1]
                 + acc[2][r] * pwu_r[2] + acc[3][r] * pwu_r[3];
        float sj = acc[0][r] * pwj_r[0] + acc[1][r] * pwj_r[1]
                 + acc[2][r] * pwj_r[2] + acc[3][r] * pwj_r[3];
        su += __shfl_xor(su, 1, 64); sj += __shfl_xor(sj, 1, 64);
        su += __shfl_xor(su, 2, 64); sj += __shfl_xor(sj, 2, 64);
        su += __shfl_xor(su, 4, 64); sj += __shfl_xor(sj, 4, 64);
        su += __shfl_xor(su, 8, 64); sj += __shfl_xor(sj, 8, 64);
        if (n16 == 0 && node < N) {
            zu[node] = su * dv;
            zj[node] = sj * dv;
        }
    }
}

// ---------------- layer-2 aggregation + prediction over scalar z tables --------------------
// out[p] = (sum_s zu[s] + zu[u])*dinv[u] + b2·pw_u + (sum_s zj[s] + zj[j])*dinv[j] + b2·pw_j + pb

__global__ __launch_bounds__(256) void k_pred(const float* __restrict__ zu, const float* __restrict__ zj,
                                              const float* __restrict__ dinv,
                                              const int2* __restrict__ rps, const int* __restrict__ srcs,
                                              const float* __restrict__ b2, const float* __restrict__ pw,
                                              const float* __restrict__ pb,
                                              const int* __restrict__ uidx, const int* __restrict__ jidx,
                                              int U, int N, int B, float* __restrict__ out) {
    int tid = threadIdx.x;
    int lane = tid & 63;
    int g = lane >> 3, t = lane & 7;
    int pair = blockIdx.x * 16 + (tid >> 6) * 4 + (g >> 1);
    if (pair >= B) return;
    int side = g & 1;
    int c = side ? (U + jidx[pair]) : uidx[pair];
    const float* zt = side ? zj : zu;

    float4 b2a = *(const float4*)(b2 + t * 8);
    float4 b2b = *(const float4*)(b2 + t * 8 + 4);
    float4 wa = *(const float4*)(pw + side * 64 + t * 8);
    float4 wb = *(const float4*)(pw + side * 64 + t * 8 + 4);
    float cpart = b2a.x * wa.x + b2a.y * wa.y + b2a.z * wa.z + b2a.w * wa.w
                + b2b.x * wb.x + b2b.y * wb.y + b2b.z * wb.z + b2b.w * wb.w;

    int2 r = rps[c];
    int deg = r.y - r.x;
    float s = 0.f;
    for (int cb = 0; cb < deg; cb += 8) {
        if (cb + t < deg) s += zt[srcs[r.x + cb + t]];
    }
    s += __shfl_xor(s, 1, 64); cpart += __shfl_xor(cpart, 1, 64);
    s += __shfl_xor(s, 2, 64); cpart += __shfl_xor(cpart, 2, 64);
    s += __shfl_xor(s, 4, 64); cpart += __shfl_xor(cpart, 4, 64);

    float val = (s + zt[c]) * dinv[c] + cpart;
    val += __shfl_xor(val, 8, 64);   // combine user+job sides of this pair
    if ((lane & 15) == 0) out[pair] = val + pb[0];
}

// ---------------- host ----------------

extern "C" void kernel_launch(void* const* d_in, const int* in_sizes, int n_in,
                              void* d_out, int out_size, void* d_ws, size_t ws_size,
                              hipStream_t stream) {
    const int*   edge = (const int*)d_in[0];
    const int*   uidx = (const int*)d_in[1];
    const int*   jidx = (const int*)d_in[2];
    const float* xu   = (const float*)d_in[3];
    const float* xj   = (const float*)d_in[4];
    const float* W1   = (const float*)d_in[5];
    const float* b1   = (const float*)d_in[6];
    const float* W2   = (const float*)d_in[7];
    const float* b2   = (const float*)d_in[8];
    const float* pw   = (const float*)d_in[9];
    const float* pb   = (const float*)d_in[10];
    float* out = (float*)d_out;

    int E = in_sizes[0] / 2;
    int B = in_sizes[1];
    int U = in_sizes[3] / D;
    int J = in_sizes[4] / D;
    int N = U + J;
    int nbuk = (N + (1 << BSHIFT) - 1) >> BSHIFT;   // 196 for N=200000; must be <= 256
    int nbin = (E + T_TILE - 1) / T_TILE;           // 521
    int nconv = (N + 127) / 128;                    // 1563 convert blocks
    const int* row = edge;       // sources
    const int* col = edge + E;   // targets

    char* p = (char*)d_ws;
    auto alloc = [&](size_t bytes) -> void* {
        void* q = (void*)p;
        p += (bytes + 255) / 256 * 256;
        return q;
    };
    size_t capsz = (size_t)nbuk * CAP * 4;               // 16.06 MB
    int*      bbase = (int*)alloc(256 * 4);
    int2*     rps   = (int2*)alloc((size_t)N * 8);
    float*    dinv  = (float*)alloc((size_t)N * 4);
    int*      srcs  = (int*)alloc(capsz);
    __half*   h     = (__half*)alloc((size_t)(N + 1) * D * 2);  // features->hidden, in-place (+ sentinel)
    unsigned* ebuf  = (unsigned*)alloc(capsz);
    float*    zu    = (float*)alloc((size_t)N * 4);      // per-node conv2·pw_u scalars
    float*    zj    = (float*)alloc((size_t)N * 4);      // per-node conv2·pw_j scalars
    __half*   WT1   = (__half*)alloc((size_t)D * D * 2); // pre-transposed W1 (fp16)
    __half*   WT2   = (__half*)alloc((size_t)D * D * 2); // pre-transposed W2 (fp16)

    hipMemsetAsync(bbase, 0, 256 * 4, stream);

    // K1: binning (521 blocks, staged/coalesced ebuf write) ∥ X fp32->fp16 convert (1563)
    // — fully independent phases; bin blocks 0/1 also transpose W1/W2 -> WT1/WT2
    k_bin_conv<<<nbin + nconv, 256, 0, stream>>>(row, col, E, nbin, bbase, ebuf, nbuk,
                                                 xu, xj, U, N, W1, W2, WT1, WT2, h);

    // K2: per-bucket degree count -> rps + dinv (+ h sentinel), 196 blocks x 1024 threads
    k_csr2a<<<nbuk, 1024, 0, stream>>>(ebuf, bbase, N, rps, dinv, h);

    // K3: srcs scatter (196 blocks) ∥ layer-1 gemm from fp16 features, in-place h (3125 blocks)
    k_csr2b_gemm1<<<nbuk + (N + 63) / 64, 256, 0, stream>>>(ebuf, rps, bbase, N, nbuk, srcs,
                                                            WT1, dinv, h);

    // K4: layer-1 aggregation (8-deep gather) + layer-2 gemm + z-projection
    k_agg_gemm2<<<(N + 63) / 64, 256, 0, stream>>>(h, dinv, rps, srcs, b1, WT2, pw, N, zu, zj);

    // K5: layer-2 aggregation over scalar z tables fused with predictor
    k_pred<<<(B + 15) / 16, 256, 0, stream>>>(zu, zj, dinv, rps, srcs, b2, pw, pb,
                                              uidx, jidx, U, N, B, out);
}

// Round 11
// 232.108 us; speedup vs baseline: 1.0539x; 1.0085x over previous
//
#include <hip/hip_runtime.h>
#include <hip/hip_fp16.h>

#define D 64
#define BSHIFT 10              // nodes per bucket = 1024
#define BMASK ((1 << BSHIFT) - 1)
#define NBUK_MAX 256
#define T_TILE 6144            // edges per bin block (256 threads x 24)
#define EPT 24                 // edges per thread in bin phase
#define CAP 20480              // per-bucket srcs/ebuf capacity (mean 16327, sigma~127)

#if defined(__has_builtin)
#if __has_builtin(__builtin_amdgcn_fdot2)
#define HAVE_FDOT2 1
#endif
#endif

typedef _Float16 h2f __attribute__((ext_vector_type(2)));
typedef _Float16 half8v __attribute__((ext_vector_type(8)));
typedef float f4v __attribute__((ext_vector_type(4)));

// inclusive wave scan (64 lanes)
__device__ __forceinline__ int wave_iscan(int v, int lane) {
#pragma unroll
    for (int off = 1; off < 64; off <<= 1) {
        int u = __shfl_up(v, off, 64);
        if (lane >= off) v += u;
    }
    return v;
}

// block-wide (256 thr) exclusive scan; returns exclusive prefix
__device__ __forceinline__ int block_escan(int v, int tid, int* wtot /*>=4 ints LDS*/) {
    int lane = tid & 63, w = tid >> 6;
    int inc = wave_iscan(v, lane);
    if (lane == 63) wtot[w] = inc;
    __syncthreads();
    int addv = 0;
#pragma unroll
    for (int q = 0; q < 4; q++) addv += (q < w) ? wtot[q] : 0;
    return inc - v + addv;
}

__device__ __forceinline__ float4 h4_to_f4(uint2 u) {
    __half2 a = *(__half2*)&u.x, b = *(__half2*)&u.y;
    float2 fa = __half22float2(a), fb = __half22float2(b);
    return make_float4(fa.x, fa.y, fb.x, fb.y);
}

// acc[0..3] += fp16x4(u) — 4 v_dot2_f32_f16 when available
__device__ __forceinline__ void acc_u2(float* acc, uint2 u) {
#ifdef HAVE_FDOT2
    h2f a0, a1;
    __builtin_memcpy(&a0, &u.x, 4);
    __builtin_memcpy(&a1, &u.y, 4);
    const h2f LO = {(_Float16)1.0f, (_Float16)0.0f};
    const h2f HI = {(_Float16)0.0f, (_Float16)1.0f};
    acc[0] = __builtin_amdgcn_fdot2(a0, LO, acc[0], false);
    acc[1] = __builtin_amdgcn_fdot2(a0, HI, acc[1], false);
    acc[2] = __builtin_amdgcn_fdot2(a1, LO, acc[2], false);
    acc[3] = __builtin_amdgcn_fdot2(a1, HI, acc[3], false);
#else
    float4 v = h4_to_f4(u);
    acc[0] += v.x; acc[1] += v.y; acc[2] += v.z; acc[3] += v.w;
#endif
}

// acc[0..7] += fp16x8(u)
__device__ __forceinline__ void acc_u4(float* acc, uint4 u) {
    uint2 a; a.x = u.x; a.y = u.y;
    uint2 b; b.x = u.z; b.y = u.w;
    acc_u2(acc, a);
    acc_u2(acc + 4, b);
}

// ---------------- fused: bucket binning (blocks [0,nbin)) + X fp32->fp16 convert (rest) ----
// Binning and the feature convert are fully independent -> overlap.
// bin: packed entry (c & BMASK) << 18 | r — requires N <= 2^18 (N=200000 here);
// bucket b's region of ebuf is [b*CAP, b*CAP + cnt_b); bbase[b] (memset 0) ends as cnt_b.
// STAGED LDS reorder for the ebuf write is essential (R9 lesson: direct 4B scatters cost
// +7us despite 2x occupancy — per-bucket runs avg 125B ~ full line only via the stage).
// Edge data read ONCE via int4 (register-cached across phases). NO global per-node atomics
// (R3 lesson). bin blocks 0/1 additionally transpose W1/W2 -> global fp16 WT.

__global__ __launch_bounds__(256) void k_bin_conv(const int* __restrict__ row, const int* __restrict__ col,
                                                  int E, int nbin, int* __restrict__ bbase,
                                                  unsigned* __restrict__ ebuf, int nbuk,
                                                  const float* __restrict__ xu, const float* __restrict__ xj,
                                                  int U, int N,
                                                  const float* __restrict__ W1, const float* __restrict__ W2,
                                                  __half* __restrict__ WT1, __half* __restrict__ WT2,
                                                  __half* __restrict__ h) {
    __shared__ int hist4[4][NBUK_MAX];     // 4 KB
    __shared__ int sexcl[NBUK_MAX];
    __shared__ int cur4[4][NBUK_MAX];      // 4 KB
    __shared__ int gbase[NBUK_MAX];
    __shared__ int wtot[4];
    __shared__ unsigned stage[T_TILE];     // 24 KB
    __shared__ unsigned char sbuk[T_TILE]; // 6 KB
    int tid = threadIdx.x;

    if ((int)blockIdx.x >= nbin) {
        // ---------- feature convert branch: 128 nodes/block, fp16(X) -> h ----------
        int m0 = ((int)blockIdx.x - nbin) * 128;
#pragma unroll
        for (int i = 0; i < 4; i++) {
            int slot = i * 256 + tid;          // 1024 slots = 128 nodes x 8 half8-chunks
            int nl = slot >> 3, q = slot & 7;
            int nn = m0 + nl;
            if (nn < N) {
                const float* src = (nn < U) ? (xu + (size_t)nn * D) : (xj + (size_t)(nn - U) * D);
                float4 a = *(const float4*)(src + q * 8);
                float4 b = *(const float4*)(src + q * 8 + 4);
                __half2 p0 = __floats2half2_rn(a.x, a.y);
                __half2 p1 = __floats2half2_rn(a.z, a.w);
                __half2 p2 = __floats2half2_rn(b.x, b.y);
                __half2 p3 = __floats2half2_rn(b.z, b.w);
                uint4 st;
                st.x = *(unsigned*)&p0; st.y = *(unsigned*)&p1;
                st.z = *(unsigned*)&p2; st.w = *(unsigned*)&p3;
                *(uint4*)(h + (size_t)nn * D + q * 8) = st;
            }
        }
        return;
    }

    // ---------- binning branch ----------
    int w = tid >> 6;
    int tile0 = blockIdx.x * T_TILE;
    int cnt = min(T_TILE, E - tile0);

    if (blockIdx.x < 2) {   // one-time W transpose: WT[c*64+k] = fp16(W[k*64+c])
        const float* Ws = blockIdx.x ? W2 : W1;
        __half* Wd = blockIdx.x ? WT2 : WT1;
#pragma unroll
        for (int i = 0; i < 16; i++) {
            int f = i * 256 + tid;           // f = k*64 + c
            int k = f >> 6, c = f & 63;
            Wd[c * 64 + k] = __float2half(Ws[f]);
        }
    }

    unsigned pk[EPT];
    int bk[EPT];

#pragma unroll
    for (int q = 0; q < 4; q++) hist4[q][tid] = 0;
    __syncthreads();
#pragma unroll
    for (int j = 0; j < EPT / 4; j++) {    // int4-vectorized edge read (order-free for binning)
        int i4 = j * 1024 + tid * 4;
        if (i4 + 3 < cnt) {
            int4 r4 = *(const int4*)(row + tile0 + i4);
            int4 c4 = *(const int4*)(col + tile0 + i4);
            int rr[4] = {r4.x, r4.y, r4.z, r4.w};
            int cc[4] = {c4.x, c4.y, c4.z, c4.w};
#pragma unroll
            for (int q = 0; q < 4; q++) {
                int jj = j * 4 + q;
                bk[jj] = cc[q] >> BSHIFT;
                pk[jj] = ((unsigned)(cc[q] & BMASK) << 18) | (unsigned)rr[q];
                atomicAdd(&hist4[w][bk[jj]], 1);
            }
        } else {
#pragma unroll
            for (int q = 0; q < 4; q++) {
                int jj = j * 4 + q;
                int i = i4 + q;
                if (i < cnt) {
                    int r = row[tile0 + i];
                    int c = col[tile0 + i];
                    bk[jj] = c >> BSHIFT;
                    pk[jj] = ((unsigned)(c & BMASK) << 18) | (unsigned)r;
                    atomicAdd(&hist4[w][bk[jj]], 1);
                } else {
                    bk[jj] = -1;
                }
            }
        }
    }
    __syncthreads();

    int h0 = hist4[0][tid], h1 = hist4[1][tid], h2 = hist4[2][tid], h3 = hist4[3][tid];
    int v = h0 + h1 + h2 + h3;
    int excl = block_escan(v, tid, wtot);
    sexcl[tid] = excl;
    cur4[0][tid] = excl;
    cur4[1][tid] = excl + h0;
    cur4[2][tid] = excl + h0 + h1;
    cur4[3][tid] = excl + h0 + h1 + h2;
    gbase[tid] = (v > 0 && tid < nbuk) ? (tid * CAP + atomicAdd(&bbase[tid], v)) : 0;
    __syncthreads();

#pragma unroll
    for (int j = 0; j < EPT; j++) {
        if (bk[j] >= 0) {
            int p = atomicAdd(&cur4[w][bk[j]], 1);
            stage[p] = pk[j];
            sbuk[p] = (unsigned char)bk[j];
        }
    }
    __syncthreads();

    for (int i = tid; i < cnt; i += 256) {
        int b = sbuk[i];
        int gpos = gbase[b] + (i - sexcl[b]);
        ebuf[gpos] = stage[i];
    }
}

// ---------------- csr2a: per-bucket degree count + rps(start,end) + dinv + h sentinel -------
// 1024 threads/block (R10 win): 16 waves/block -> 4x loads+atomics in flight vs 256thr.

__global__ __launch_bounds__(1024) void k_csr2a(const unsigned* __restrict__ ebuf,
                                                const int* __restrict__ bbase, int N,
                                                int2* __restrict__ rps, float* __restrict__ dinv,
                                                __half* __restrict__ h) {
    __shared__ int lcnt[1 << BSHIFT];  // 4 KB
    __shared__ int wtot[16];
    int tid = threadIdx.x;
    int c0 = blockIdx.x << BSHIFT;
    int nn = min(1 << BSHIFT, N - c0);
    int e0 = blockIdx.x * CAP, e1 = e0 + bbase[blockIdx.x];

    if (blockIdx.x == 0 && tid < 16) {  // zero h sentinel row (gather padding target)
        uint2 z; z.x = 0u; z.y = 0u;
        *(uint2*)(h + (size_t)N * D + tid * 4) = z;
    }

    lcnt[tid] = 0;
    __syncthreads();
    int len = e1 - e0;
    int nf = len & ~3;
    for (int j = tid * 4; j < nf; j += 4096) {       // uint4-vectorized count
        uint4 v = *(const uint4*)(ebuf + e0 + j);
        atomicAdd(&lcnt[v.x >> 18], 1);
        atomicAdd(&lcnt[v.y >> 18], 1);
        atomicAdd(&lcnt[v.z >> 18], 1);
        atomicAdd(&lcnt[v.w >> 18], 1);
    }
    if (tid < (len - nf)) atomicAdd(&lcnt[ebuf[e0 + nf + tid] >> 18], 1);
    __syncthreads();

    // 1024-thread exclusive scan (one node per thread)
    int c = lcnt[tid];
    int lane = tid & 63, w = tid >> 6;
    int inc = wave_iscan(c, lane);
    if (lane == 63) wtot[w] = inc;
    __syncthreads();
    int addv = 0;
#pragma unroll
    for (int q = 0; q < 16; q++) addv += (q < w) ? wtot[q] : 0;
    int excl = inc - c + addv;

    if (tid < nn) {
        int st = e0 + excl;
        rps[c0 + tid] = make_int2(st, st + c);
        dinv[c0 + tid] = rsqrtf((float)(c + 1));  // +1 self loop
    }
}

// stage pre-transposed global WT (fp16, [c][k] dense 64x64) into LDS (stride 72), 256 thr.
__device__ __forceinline__ void stage_Wt(const __half* __restrict__ WTg, __half* __restrict__ Wt, int tid) {
#pragma unroll
    for (int i = 0; i < 2; i++) {
        int f = (i * 256 + tid) * 8;      // 4096 halves total
        int c = f >> 6, k = f & 63;
        *(half8v*)(Wt + c * 72 + k) = *(const half8v*)(WTg + f);
    }
}

// ---------------- fused: csr2b srcs scatter (blocks [0,nbuk)) + gemm layer-1 (rest) ----------
// 1024 threads (R11): scatter gets 4x parallelism (csr2a's R10 win applied); gemm branch does
// 256 nodes/block with DIRECT global A-loads (no Xh LDS stage — each lane's MFMA fragment is
// a contiguous 16B of an h row; L1 merges same-line requests). The single barrier after the
// loads (hipcc emits s_waitcnt vmcnt(0) before s_barrier) orders all in-place h reads before
// any h write within the block; tiles are block-disjoint so no cross-block hazard.

__global__ __launch_bounds__(1024) void k_csr2b_gemm1(const unsigned* __restrict__ ebuf,
                                                      const int2* __restrict__ rps,
                                                      const int* __restrict__ bbase,
                                                      int N, int nbuk, int* __restrict__ srcs,
                                                      const __half* __restrict__ WT1,
                                                      const float* __restrict__ dinv, __half* __restrict__ h) {
    __shared__ __align__(16) __half Wt[64 * 72];   // 9.2 KB
    __shared__ int lcur[1 << BSHIFT];              // 4 KB (scatter branch)
    int tid = threadIdx.x;
    if ((int)blockIdx.x < nbuk) {
        int c0 = blockIdx.x << BSHIFT;
        int e0 = blockIdx.x * CAP, e1 = e0 + bbase[blockIdx.x];
        lcur[tid] = (c0 + tid < N) ? rps[c0 + tid].x : 0;
        __syncthreads();
        int len = e1 - e0;
        int nf = len & ~3;
        for (int j = tid * 4; j < nf; j += 4096) {   // uint4-vectorized scatter
            uint4 v = *(const uint4*)(ebuf + e0 + j);
            int p0 = atomicAdd(&lcur[v.x >> 18], 1); srcs[p0] = (int)(v.x & 0x3ffffu);
            int p1 = atomicAdd(&lcur[v.y >> 18], 1); srcs[p1] = (int)(v.y & 0x3ffffu);
            int p2 = atomicAdd(&lcur[v.z >> 18], 1); srcs[p2] = (int)(v.z & 0x3ffffu);
            int p3 = atomicAdd(&lcur[v.w >> 18], 1); srcs[p3] = (int)(v.w & 0x3ffffu);
        }
        if (tid < (len - nf)) {
            unsigned pk = ebuf[e0 + nf + tid];
            int p = atomicAdd(&lcur[pk >> 18], 1);
            srcs[p] = (int)(pk & 0x3ffffu);
        }
    } else {
        int n0 = ((int)blockIdx.x - nbuk) * 256;     // 256 nodes per block (16 waves x 16)
        if (tid < 512) {                              // stage Wt (4096 halves, 512 x half8)
            int f = tid * 8;
            int c = f >> 6, k = f & 63;
            *(half8v*)(Wt + c * 72 + k) = *(const half8v*)(WT1 + f);
        }
        int lane = tid & 63;
        int wv = tid >> 6;                            // 0..15
        int n16 = lane & 15, quad = lane >> 4;
        int nodeA = n0 + wv * 16 + n16;
        half8v a0 = {(_Float16)0.f, (_Float16)0.f, (_Float16)0.f, (_Float16)0.f,
                     (_Float16)0.f, (_Float16)0.f, (_Float16)0.f, (_Float16)0.f};
        half8v a1 = a0;
        if (nodeA < N) {                              // direct global A-fragment loads
            a0 = *(const half8v*)(h + (size_t)nodeA * D + quad * 8);
            a1 = *(const half8v*)(h + (size_t)nodeA * D + quad * 8 + 32);
        }
        __syncthreads();   // Wt staged + ALL in-place h reads complete before any write

        f4v acc[4];
#pragma unroll
        for (int ct = 0; ct < 4; ct++) {
            acc[ct] = (f4v){0.f, 0.f, 0.f, 0.f};
            const __half* wp = Wt + (ct * 16 + n16) * 72;
            half8v b0 = *(const half8v*)(wp + quad * 8);
            half8v b1 = *(const half8v*)(wp + quad * 8 + 32);
            acc[ct] = __builtin_amdgcn_mfma_f32_16x16x32_f16(a0, b0, acc[ct], 0, 0, 0);
            acc[ct] = __builtin_amdgcn_mfma_f32_16x16x32_f16(a1, b1, acc[ct], 0, 0, 0);
        }
#pragma unroll
        for (int r = 0; r < 4; r++) {
            int node = n0 + wv * 16 + quad * 4 + r;
            if (node < N) {
                float dv = dinv[node];
#pragma unroll
                for (int ct = 0; ct < 4; ct++)
                    h[(size_t)node * D + ct * 16 + n16] = __float2half(acc[ct][r] * dv);
            }
        }
    }
}

// ---------------- gather: 8 lanes per node, 8 nodes per wave-round ----------------
// lane = g*8+t; group g owns one node; lane t owns features [8t,8t+8) (uint4 = 16 B).
// 8 edge indices preloaded per group (sentinel N at load); all 8 dwordx4 gathers issued
// back-to-back (128 B in flight per lane). Proven optimal depth (R7: 16-deep was neutral
// on time and cost occupancy — agg is at the random-128B serving ceiling, not MLP-bound).

__device__ __forceinline__ void gather8(float* acc, const __half* __restrict__ hs,
                                        const int2* __restrict__ rps,
                                        const int* __restrict__ srcs,
                                        int node, int N, int g, int t) {
    const __half* hp = hs + t * 8;
    int2 r = rps[node];
    int e0 = r.x, deg = r.y - r.x;
    for (int cb = 0; cb < deg; cb += 8) {
        int sv = (cb + t < deg) ? srcs[e0 + cb + t] : N;
        int base = g * 8;
        int s0 = __shfl(sv, base + 0, 64);
        int s1 = __shfl(sv, base + 1, 64);
        int s2 = __shfl(sv, base + 2, 64);
        int s3 = __shfl(sv, base + 3, 64);
        int s4 = __shfl(sv, base + 4, 64);
        int s5 = __shfl(sv, base + 5, 64);
        int s6 = __shfl(sv, base + 6, 64);
        int s7 = __shfl(sv, base + 7, 64);
        uint4 u0 = *(const uint4*)(hp + (size_t)s0 * D);
        uint4 u1 = *(const uint4*)(hp + (size_t)s1 * D);
        uint4 u2 = *(const uint4*)(hp + (size_t)s2 * D);
        uint4 u3 = *(const uint4*)(hp + (size_t)s3 * D);
        uint4 u4 = *(const uint4*)(hp + (size_t)s4 * D);
        uint4 u5 = *(const uint4*)(hp + (size_t)s5 * D);
        uint4 u6 = *(const uint4*)(hp + (size_t)s6 * D);
        uint4 u7 = *(const uint4*)(hp + (size_t)s7 * D);
        acc_u4(acc, u0);
        acc_u4(acc, u1);
        acc_u4(acc, u2);
        acc_u4(acc, u3);
        acc_u4(acc, u4);
        acc_u4(acc, u5);
        acc_u4(acc, u6);
        acc_u4(acc, u7);
    }
}

// ---------------- fused: layer-1 aggregation + layer-2 gemm + z-projection epilogue --------
// agg: conv1 = (sum_s h[s] + h[c]) * dinv[c] + b1, relu'd into MFMA A-tile. MFMA with W2.
// Epilogue reduces the accumulator tile against pred weights, emitting per-node scalars
// zu[n] = dinv[n]*(A1[n]@W2)·pw_u and zj[n] (no hs2 materialization).

__global__ __launch_bounds__(256) void k_agg_gemm2(const __half* __restrict__ hs, const float* __restrict__ dinv,
                                                   const int2* __restrict__ rps, const int* __restrict__ srcs,
                                                   const float* __restrict__ bias, const __half* __restrict__ WT2,
                                                   const float* __restrict__ pw, int N,
                                                   float* __restrict__ zu, float* __restrict__ zj) {
    __shared__ __align__(16) __half Xh[64 * 72];
    __shared__ __align__(16) __half Wt[64 * 72];
    int tid = threadIdx.x;
    int lane = tid & 63;
    int w = tid >> 6;
    int g = lane >> 3, t = lane & 7;
    int n0 = blockIdx.x * 64;

    stage_Wt(WT2, Wt, tid);

    float4 ba = *(const float4*)(bias + t * 8);
    float4 bb = *(const float4*)(bias + t * 8 + 4);
#pragma unroll
    for (int rr = 0; rr < 2; rr++) {
        int nl = w * 16 + rr * 8 + g;
        int node = n0 + nl;
        uint4 st; st.x = 0u; st.y = 0u; st.z = 0u; st.w = 0u;
        if (node < N) {
            float acc[8] = {0.f, 0.f, 0.f, 0.f, 0.f, 0.f, 0.f, 0.f};
            gather8(acc, hs, rps, srcs, node, N, g, t);
            uint4 su = *(const uint4*)(hs + (size_t)node * D + t * 8);
            float4 sa = h4_to_f4(make_uint2(su.x, su.y));
            float4 sb = h4_to_f4(make_uint2(su.z, su.w));
            float dv = dinv[node];
            float o0 = fmaxf((acc[0] + sa.x) * dv + ba.x, 0.f);
            float o1 = fmaxf((acc[1] + sa.y) * dv + ba.y, 0.f);
            float o2 = fmaxf((acc[2] + sa.z) * dv + ba.z, 0.f);
            float o3 = fmaxf((acc[3] + sa.w) * dv + ba.w, 0.f);
            float o4 = fmaxf((acc[4] + sb.x) * dv + bb.x, 0.f);
            float o5 = fmaxf((acc[5] + sb.y) * dv + bb.y, 0.f);
            float o6 = fmaxf((acc[6] + sb.z) * dv + bb.z, 0.f);
            float o7 = fmaxf((acc[7] + sb.w) * dv + bb.w, 0.f);
            __half2 p0 = __floats2half2_rn(o0, o1);
            __half2 p1 = __floats2half2_rn(o2, o3);
            __half2 p2 = __floats2half2_rn(o4, o5);
            __half2 p3 = __floats2half2_rn(o6, o7);
            st.x = *(unsigned*)&p0; st.y = *(unsigned*)&p1;
            st.z = *(unsigned*)&p2; st.w = *(unsigned*)&p3;
        }
        *(uint4*)(Xh + nl * 72 + t * 8) = st;
    }
    __syncthreads();

    // ---- MFMA with W2 + z-projection epilogue (no hs2 write) ----
    int wv = w;
    int n16 = lane & 15, quad = lane >> 4;
    const __half* Xw = Xh + (wv * 16) * 72;
    half8v a0 = *(const half8v*)(Xw + n16 * 72 + quad * 8);
    half8v a1 = *(const half8v*)(Xw + n16 * 72 + quad * 8 + 32);
    f4v acc[4];
    float pwu_r[4], pwj_r[4];
#pragma unroll
    for (int ct = 0; ct < 4; ct++) {
        pwu_r[ct] = pw[ct * 16 + n16];
        pwj_r[ct] = pw[64 + ct * 16 + n16];
        acc[ct] = (f4v){0.f, 0.f, 0.f, 0.f};
        const __half* wp = Wt + (ct * 16 + n16) * 72;
        half8v b0 = *(const half8v*)(wp + quad * 8);
        half8v b1 = *(const half8v*)(wp + quad * 8 + 32);
        acc[ct] = __builtin_amdgcn_mfma_f32_16x16x32_f16(a0, b0, acc[ct], 0, 0, 0);
        acc[ct] = __builtin_amdgcn_mfma_f32_16x16x32_f16(a1, b1, acc[ct], 0, 0, 0);
    }
#pragma unroll
    for (int r = 0; r < 4; r++) {
        int node = n0 + wv * 16 + quad * 4 + r;
        float dv = (node < N) ? dinv[node] : 0.0f;
        float su = acc[0][r] * pwu_r[0] + acc[1][r] * pwu_r[1]
                 + acc[2][r] * pwu_r[2] + acc[3][r] * pwu_r[3];
        float sj = acc[0][r] * pwj_r[0] + acc[1][r] * pwj_r[1]
                 + acc[2][r] * pwj_r[2] + acc[3][r] * pwj_r[3];
        su += __shfl_xor(su, 1, 64); sj += __shfl_xor(sj, 1, 64);
        su += __shfl_xor(su, 2, 64); sj += __shfl_xor(sj, 2, 64);
        su += __shfl_xor(su, 4, 64); sj += __shfl_xor(sj, 4, 64);
        su += __shfl_xor(su, 8, 64); sj += __shfl_xor(sj, 8, 64);
        if (n16 == 0 && node < N) {
            zu[node] = su * dv;
            zj[node] = sj * dv;
        }
    }
}

// ---------------- layer-2 aggregation + prediction over scalar z tables --------------------
// out[p] = (sum_s zu[s] + zu[u])*dinv[u] + b2·pw_u + (sum_s zj[s] + zj[j])*dinv[j] + b2·pw_j + pb

__global__ __launch_bounds__(256) void k_pred(const float* __restrict__ zu, const float* __restrict__ zj,
                                              const float* __restrict__ dinv,
                                              const int2* __restrict__ rps, const int* __restrict__ srcs,
                                              const float* __restrict__ b2, const float* __restrict__ pw,
                                              const float* __restrict__ pb,
                                              const int* __restrict__ uidx, const int* __restrict__ jidx,
                                              int U, int N, int B, float* __restrict__ out) {
    int tid = threadIdx.x;
    int lane = tid & 63;
    int g = lane >> 3, t = lane & 7;
    int pair = blockIdx.x * 16 + (tid >> 6) * 4 + (g >> 1);
    if (pair >= B) return;
    int side = g & 1;
    int c = side ? (U + jidx[pair]) : uidx[pair];
    const float* zt = side ? zj : zu;

    float4 b2a = *(const float4*)(b2 + t * 8);
    float4 b2b = *(const float4*)(b2 + t * 8 + 4);
    float4 wa = *(const float4*)(pw + side * 64 + t * 8);
    float4 wb = *(const float4*)(pw + side * 64 + t * 8 + 4);
    float cpart = b2a.x * wa.x + b2a.y * wa.y + b2a.z * wa.z + b2a.w * wa.w
                + b2b.x * wb.x + b2b.y * wb.y + b2b.z * wb.z + b2b.w * wb.w;

    int2 r = rps[c];
    int deg = r.y - r.x;
    float s = 0.f;
    for (int cb = 0; cb < deg; cb += 8) {
        if (cb + t < deg) s += zt[srcs[r.x + cb + t]];
    }
    s += __shfl_xor(s, 1, 64); cpart += __shfl_xor(cpart, 1, 64);
    s += __shfl_xor(s, 2, 64); cpart += __shfl_xor(cpart, 2, 64);
    s += __shfl_xor(s, 4, 64); cpart += __shfl_xor(cpart, 4, 64);

    float val = (s + zt[c]) * dinv[c] + cpart;
    val += __shfl_xor(val, 8, 64);   // combine user+job sides of this pair
    if ((lane & 15) == 0) out[pair] = val + pb[0];
}

// ---------------- host ----------------

extern "C" void kernel_launch(void* const* d_in, const int* in_sizes, int n_in,
                              void* d_out, int out_size, void* d_ws, size_t ws_size,
                              hipStream_t stream) {
    const int*   edge = (const int*)d_in[0];
    const int*   uidx = (const int*)d_in[1];
    const int*   jidx = (const int*)d_in[2];
    const float* xu   = (const float*)d_in[3];
    const float* xj   = (const float*)d_in[4];
    const float* W1   = (const float*)d_in[5];
    const float* b1   = (const float*)d_in[6];
    const float* W2   = (const float*)d_in[7];
    const float* b2   = (const float*)d_in[8];
    const float* pw   = (const float*)d_in[9];
    const float* pb   = (const float*)d_in[10];
    float* out = (float*)d_out;

    int E = in_sizes[0] / 2;
    int B = in_sizes[1];
    int U = in_sizes[3] / D;
    int J = in_sizes[4] / D;
    int N = U + J;
    int nbuk = (N + (1 << BSHIFT) - 1) >> BSHIFT;   // 196 for N=200000; must be <= 256
    int nbin = (E + T_TILE - 1) / T_TILE;           // 521
    int nconv = (N + 127) / 128;                    // 1563 convert blocks
    int ngemm = (N + 255) / 256;                    // 782 gemm1 blocks (256 nodes each)
    const int* row = edge;       // sources
    const int* col = edge + E;   // targets

    char* p = (char*)d_ws;
    auto alloc = [&](size_t bytes) -> void* {
        void* q = (void*)p;
        p += (bytes + 255) / 256 * 256;
        return q;
    };
    size_t capsz = (size_t)nbuk * CAP * 4;               // 16.06 MB
    int*      bbase = (int*)alloc(256 * 4);
    int2*     rps   = (int2*)alloc((size_t)N * 8);
    float*    dinv  = (float*)alloc((size_t)N * 4);
    int*      srcs  = (int*)alloc(capsz);
    __half*   h     = (__half*)alloc((size_t)(N + 1) * D * 2);  // features->hidden, in-place (+ sentinel)
    unsigned* ebuf  = (unsigned*)alloc(capsz);
    float*    zu    = (float*)alloc((size_t)N * 4);      // per-node conv2·pw_u scalars
    float*    zj    = (float*)alloc((size_t)N * 4);      // per-node conv2·pw_j scalars
    __half*   WT1   = (__half*)alloc((size_t)D * D * 2); // pre-transposed W1 (fp16)
    __half*   WT2   = (__half*)alloc((size_t)D * D * 2); // pre-transposed W2 (fp16)

    hipMemsetAsync(bbase, 0, 256 * 4, stream);

    // K1: binning (521 blocks, staged/coalesced ebuf write) ∥ X fp32->fp16 convert (1563)
    // — fully independent phases; bin blocks 0/1 also transpose W1/W2 -> WT1/WT2
    k_bin_conv<<<nbin + nconv, 256, 0, stream>>>(row, col, E, nbin, bbase, ebuf, nbuk,
                                                 xu, xj, U, N, W1, W2, WT1, WT2, h);

    // K2: per-bucket degree count -> rps + dinv (+ h sentinel), 196 blocks x 1024 threads
    k_csr2a<<<nbuk, 1024, 0, stream>>>(ebuf, bbase, N, rps, dinv, h);

    // K3: srcs scatter (196 wide blocks) ∥ layer-1 gemm, direct-load A, in-place h (782 blocks)
    k_csr2b_gemm1<<<nbuk + ngemm, 1024, 0, stream>>>(ebuf, rps, bbase, N, nbuk, srcs,
                                                     WT1, dinv, h);

    // K4: layer-1 aggregation (8-deep gather) + layer-2 gemm + z-projection
    k_agg_gemm2<<<(N + 63) / 64, 256, 0, stream>>>(h, dinv, rps, srcs, b1, WT2, pw, N, zu, zj);

    // K5: layer-2 aggregation over scalar z tables fused with predictor
    k_pred<<<(B + 15) / 16, 256, 0, stream>>>(zu, zj, dinv, rps, srcs, b2, pw, pb,
                                              uidx, jidx, U, N, B, out);
}